// Round 6
// baseline (306.228 us; speedup 1.0000x reference)
//
#include <hip/hip_runtime.h>
#include <math.h>

// Problem constants (reference: B,H,Q_TOK,D = 8,12,577,64)
constexpr int BB = 8, HH = 12, QT = 577, DD = 64;
constexpr int NTOK = BB * HH * QT;                        // 55392 tokens
constexpr long long MASK_ELEMS = (long long)NTOK * QT;    // 31,961,184
constexpr int NBH = BB * HH;                              // 96 bh-rows per q
constexpr int WAVES_PER_BLOCK = 4;                        // 256 threads
constexpr int CHUNKS = NBH / WAVES_PER_BLOCK;             // 24

using f4 = __attribute__((ext_vector_type(4))) float;

// Verified mask math (R2-R5): hq = j0*g0+j1*g1+j2*g2; E = exp(hq) = 1/p
// (row max of p is exactly 1); mask = u/(u+(E-1)*(1-u)) [T==1].
// Edges exact: hq==0 -> E=1 -> m~=1 (ref 1.0); E=inf -> m=0 (ref 0).
template<bool T1>
__device__ __forceinline__ float mask_elem(float g0, float g1, float g2,
                                           float j0, float j1, float j2,
                                           float uv, float invT)
{
    const float hq = fmaxf(fmaf(j2, g2, fmaf(j1, g1, j0 * g0)), 0.0f);
    const float E  = __expf(hq);                 // hq==0 -> exactly 1
    const float a  = E - 1.0f;
    if (T1)
        return __fdividef(uv, fmaf(a, 1.0f - uv, uv));
    const float rr = __fdividef(a * (1.0f - uv), uv);
    return __fdividef(1.0f, 1.0f + __expf(__logf(rr) * invT));
}

// Register geometry for key index kk in [0,576]: patch (row,col) = ((kk-1)/24,
// (kk-1)%24), CLS (kk==0) zero. /24 via magic: (t>>3)/3 = mulhi(t>>3,0xAAAAAAAB)>>1.
// GUARD0 compiled in only for the single combo that can reach kk==0.
template<bool GUARD0>
__device__ __forceinline__ void geom3(int kk, float fqr, float fqc, float sc,
                                      float& g0, float& g1, float& g2)
{
    const unsigned t  = (unsigned)(kk - 1);
    const unsigned kr = __umulhi(t >> 3, 0xAAAAAAABu) >> 1;   // (kk-1)/24
    const unsigned kc = t - kr * 24u;
    float dy = (fqr - (float)(int)kr) * sc;      // sc=0 zeroes the q==0 row
    float dx = (fqc - (float)(int)kc) * sc;
    if (GUARD0) { if (kk == 0) { dy = 0.0f; dx = 0.0f; } }
    g0 = dy * dy; g1 = dy * dx; g2 = dx * dx;
}

template<bool T1>
__device__ __forceinline__ void mask_row(int h, int NV, int lane,
                                         f4 uu0, f4 uu1, f4 uu2, int idx2,
                                         int scnt, int ks, float us,
                                         float fqr, float fqc, float sc,
                                         float j0, float j1, float j2,
                                         float invT,
                                         float* __restrict__ mp,
                                         float* __restrict__ out, unsigned base)
{
    const int kl = h + 4 * lane;                 // kk = kl + c + 256*p
    {
        f4 m4;
#pragma unroll
        for (int c = 0; c < 4; ++c) {
            float g0, g1, g2;
            if (c == 0) geom3<true >(kl + c, fqr, fqc, sc, g0, g1, g2);
            else        geom3<false>(kl + c, fqr, fqc, sc, g0, g1, g2);
            m4[c] = mask_elem<T1>(g0, g1, g2, j0, j1, j2, uu0[c], invT);
        }
        __builtin_nontemporal_store(m4, (f4*)(mp + 4 * lane));
    }
    {
        f4 m4;
#pragma unroll
        for (int c = 0; c < 4; ++c) {
            float g0, g1, g2;
            geom3<false>(kl + 256 + c, fqr, fqc, sc, g0, g1, g2);
            m4[c] = mask_elem<T1>(g0, g1, g2, j0, j1, j2, uu1[c], invT);
        }
        __builtin_nontemporal_store(m4, (f4*)(mp + 4 * (64 + lane)));
    }
    if (idx2 < NV) {                             // pass 2: lanes 0..14/15
        f4 m4;
#pragma unroll
        for (int c = 0; c < 4; ++c) {
            float g0, g1, g2;
            geom3<false>(kl + 512 + c, fqr, fqc, sc, g0, g1, g2);
            m4[c] = mask_elem<T1>(g0, g1, g2, j0, j1, j2, uu2[c], invT);
        }
        __builtin_nontemporal_store(m4, (f4*)(mp + 4 * idx2));
    }
    if (lane < scnt) {                           // head/tail leftovers (1 or 5)
        float g0, g1, g2;
        geom3<true>(ks, fqr, fqc, sc, g0, g1, g2);
        const float m = mask_elem<T1>(g0, g1, g2, j0, j1, j2, us, invT);
        __builtin_nontemporal_store(m, out + base + ks);
    }
}

// ---------------------------------------------------------------------------
// FUSED, ZERO-LDS, ZERO-BARRIER kernel. One wave per token row. All global
// loads (u row vec4s, query, temp) issue at wave start; the ~800-cycle MLP
// chain hides their latency; geometry is computed in registers (magic /24)
// and W1 comes from global (16 KB, L1-resident) with explicit readlane
// broadcast -- the LDS pipe (measured ~74% busy in R5) is now untouched
// except for the 18-op butterfly reduce.
// ---------------------------------------------------------------------------
__global__ __launch_bounds__(256, 8)
void fused_reg(const float* __restrict__ query,  // (NTOK, 64)
               const float* __restrict__ W1,     // (64, 64)
               const float* __restrict__ b1,     // (64)
               const float* __restrict__ W2,     // (64, 3)
               const float* __restrict__ b2,     // (3)
               const float* __restrict__ u,      // (NTOK*577) flat
               const float* __restrict__ temp,   // (1)
               float* __restrict__ out)          // mask then Sigma
{
    f4* __restrict__ SigOut = (f4*)(out + MASK_ELEMS);
    const int q     = blockIdx.x;                 // 0..576
    const int chunk = blockIdx.y;                 // 0..23
    const int wave  = threadIdx.x >> 6, lane = threadIdx.x & 63;

    const int token = (chunk * WAVES_PER_BLOCK + wave) * QT + q;
    const unsigned base = (unsigned)token * (unsigned)QT;
    const int h  = (int)((0u - base) & 3u);       // scalars to 16B align
    const int NV = (QT - h) >> 2;                 // 143 or 144 vec4s
    const float* __restrict__ up = u   + base + h;
    float*       __restrict__ mp = out + base + h;

    // ---- issue ALL global loads up-front (drain under the MLP) ----
    const f4 uu0 = *(const f4*)(up + 4 * lane);
    const f4 uu1 = *(const f4*)(up + 4 * (64 + lane));
    const int idx2 = 128 + lane;
    f4 uu2 = {};
    if (idx2 < NV) uu2 = *(const f4*)(up + 4 * idx2);
    const int scnt = QT - 4 * NV;                 // 1 or 5 leftovers
    int ks = 0; float us = 0.0f;
    if (lane < scnt) {
        ks = (lane < h) ? lane : (h + 4 * NV + (lane - h));
        us = u[base + ks];
    }
    const float tval = temp[0];
    const float qv   = query[(size_t)token * DD + lane];

    // ---- MLP (verified math; W1 via global/L1, readlane broadcast) ----
    float acc = b1[lane];
#pragma unroll
    for (int i = 0; i < DD; ++i) {
        const float w = W1[i * DD + lane];        // coalesced, L1-hit
        const float x = __int_as_float(
            __builtin_amdgcn_readlane(__float_as_int(qv), i));
        acc = fmaf(x, w, acc);
    }
    const float hg = 0.5f * acc * (1.0f + erff(acc * 0.7071067811865476f));

    float p0 = hg * W2[lane * 3 + 0];
    float p1 = hg * W2[lane * 3 + 1];
    float p2 = hg * W2[lane * 3 + 2];
#pragma unroll
    for (int off = 32; off > 0; off >>= 1) {      // butterfly: all lanes get sums
        p0 += __shfl_xor(p0, off);
        p1 += __shfl_xor(p1, off);
        p2 += __shfl_xor(p2, off);
    }
    const float sy  = expf(p0 + b2[0]) + 1.0f;    // precise ocml for Sigma
    const float sx  = expf(p1 + b2[1]) + 1.0f;
    const float rho = tanhf(p2 + b2[2]) * 0.99f;
    const float cov = sy * sx * rho;
    const float Sx = sy * sy, Sw = sx * sx, Sy = cov;
    if (lane == 0) {
        f4 s; s.x = Sx; s.y = Sy; s.z = Sy; s.w = Sw;
        SigOut[token] = s;                        // Sigma output region
    }

    const float rdet = __fdividef(1.0f, fmaf(Sx, Sw, -Sy * Sy));
    const float j0 =  0.5f * Sw * rdet;           // 0.5*inv00
    const float j1 = -Sy * rdet;                  // inv01 (x2, x0.5 cancel)
    const float j2 =  0.5f * Sx * rdet;           // 0.5*inv11

    // per-q scalars (block-uniform -> SALU)
    const int qm1 = (q > 0) ? q - 1 : 0;
    const int qr  = (int)((unsigned)qm1 / 24u);
    const int qc  = qm1 - qr * 24;
    const float fqr = (float)qr, fqc = (float)qc;
    const float sc  = (q == 0) ? 0.0f : 1.0f;     // zero the q==0 (CLS) row

    // scalar-uniform temperature branch: hot path has NO predicated cold ops
    const float invT = __int_as_float(__builtin_amdgcn_readfirstlane(
                           __float_as_int(__fdividef(1.0f, tval))));
    if (invT == 1.0f)
        mask_row<true >(h, NV, lane, uu0, uu1, uu2, idx2, scnt, ks, us,
                        fqr, fqc, sc, j0, j1, j2, invT, mp, out, base);
    else
        mask_row<false>(h, NV, lane, uu0, uu1, uu2, idx2, scnt, ks, us,
                        fqr, fqc, sc, j0, j1, j2, invT, mp, out, base);
}

extern "C" void kernel_launch(void* const* d_in, const int* in_sizes, int n_in,
                              void* d_out, int out_size, void* d_ws, size_t ws_size,
                              hipStream_t stream) {
    const float* query = (const float*)d_in[0];
    const float* W1    = (const float*)d_in[1];
    const float* b1    = (const float*)d_in[2];
    const float* W2    = (const float*)d_in[3];
    const float* b2    = (const float*)d_in[4];
    // d_in[5] = dists: closed form inside fused_reg
    const float* u     = (const float*)d_in[6];
    const float* temp  = (const float*)d_in[7];
    float* out = (float*)d_out;

    fused_reg<<<dim3(QT, CHUNKS), dim3(256), 0, stream>>>(
        query, W1, b1, W2, b2, u, temp, out);
}

// Round 7
// 258.148 us; speedup vs baseline: 1.1863x; 1.1863x over previous
//
#include <hip/hip_runtime.h>
#include <math.h>

// Problem constants (reference: B,H,Q_TOK,D = 8,12,577,64)
constexpr int BB = 8, HH = 12, QT = 577, DD = 64;
constexpr int NTOK = BB * HH * QT;                        // 55392 tokens
constexpr long long MASK_ELEMS = (long long)NTOK * QT;    // 31,961,184
constexpr int NBH = BB * HH;                              // 96 bh-rows per q
constexpr int WAVES_PER_BLOCK = 8;                        // 512 threads
constexpr int CHUNKS = NBH / WAVES_PER_BLOCK;             // 12

using f4 = __attribute__((ext_vector_type(4))) float;

// Verified mask math (R2-R6): hq = j0*g0+j1*g1+j2*g2; E = exp(hq) = 1/p
// (row max of p is exactly 1); mask = u/(u+(E-1)*(1-u)) [T==1].
// Edges exact: hq==0 -> E=1 -> m~=1 (ref 1.0); E=inf -> m=0 (ref 0).
template<bool T1>
__device__ __forceinline__ float mask_elem(float g0, float g1, float g2,
                                           float j0, float j1, float j2,
                                           float uv, float invT)
{
    const float hq = fmaxf(fmaf(j2, g2, fmaf(j1, g1, j0 * g0)), 0.0f);
    const float E  = __expf(hq);                 // hq==0 -> exactly 1
    const float a  = E - 1.0f;
    if (T1)
        return __fdividef(uv, fmaf(a, 1.0f - uv, uv));
    const float rr = __fdividef(a * (1.0f - uv), uv);
    return __fdividef(1.0f, 1.0f + __expf(__logf(rr) * invT));
}

// Register geometry (verified R6): patch (row,col) = ((kk-1)/24, (kk-1)%24),
// CLS (kk==0) zero. /24 via magic: (t>>3)/3 = mulhi(t>>3,0xAAAAAAAB)>>1.
template<bool GUARD0>
__device__ __forceinline__ void geom3(int kk, float fqr, float fqc, float sc,
                                      float& g0, float& g1, float& g2)
{
    const unsigned t  = (unsigned)(kk - 1);
    const unsigned kr = __umulhi(t >> 3, 0xAAAAAAABu) >> 1;   // (kk-1)/24
    const unsigned kc = t - kr * 24u;
    float dy = (fqr - (float)(int)kr) * sc;      // sc=0 zeroes the q==0 row
    float dx = (fqc - (float)(int)kc) * sc;
    if (GUARD0) { if (kk == 0) { dy = 0.0f; dx = 0.0f; } }
    g0 = dy * dy; g1 = dy * dx; g2 = dx * dx;
}

// Verified R6 mask row (register geometry, aligned vec4 passes + leftovers).
template<bool T1>
__device__ __forceinline__ void mask_row(int h, int NV, int lane,
                                         f4 uu0, f4 uu1, f4 uu2, int idx2,
                                         int scnt, int ks, float us,
                                         float fqr, float fqc, float sc,
                                         float j0, float j1, float j2,
                                         float invT,
                                         float* __restrict__ mp,
                                         float* __restrict__ out, unsigned base)
{
    const int kl = h + 4 * lane;                 // kk = kl + c + 256*p
    {
        f4 m4;
#pragma unroll
        for (int c = 0; c < 4; ++c) {
            float g0, g1, g2;
            if (c == 0) geom3<true >(kl + c, fqr, fqc, sc, g0, g1, g2);
            else        geom3<false>(kl + c, fqr, fqc, sc, g0, g1, g2);
            m4[c] = mask_elem<T1>(g0, g1, g2, j0, j1, j2, uu0[c], invT);
        }
        __builtin_nontemporal_store(m4, (f4*)(mp + 4 * lane));
    }
    {
        f4 m4;
#pragma unroll
        for (int c = 0; c < 4; ++c) {
            float g0, g1, g2;
            geom3<false>(kl + 256 + c, fqr, fqc, sc, g0, g1, g2);
            m4[c] = mask_elem<T1>(g0, g1, g2, j0, j1, j2, uu1[c], invT);
        }
        __builtin_nontemporal_store(m4, (f4*)(mp + 4 * (64 + lane)));
    }
    if (idx2 < NV) {                             // pass 2: lanes 0..14/15
        f4 m4;
#pragma unroll
        for (int c = 0; c < 4; ++c) {
            float g0, g1, g2;
            geom3<false>(kl + 512 + c, fqr, fqc, sc, g0, g1, g2);
            m4[c] = mask_elem<T1>(g0, g1, g2, j0, j1, j2, uu2[c], invT);
        }
        __builtin_nontemporal_store(m4, (f4*)(mp + 4 * idx2));
    }
    if (lane < scnt) {                           // head/tail leftovers (1 or 5)
        float g0, g1, g2;
        geom3<true>(ks, fqr, fqc, sc, g0, g1, g2);
        const float m = mask_elem<T1>(g0, g1, g2, j0, j1, j2, us, invT);
        __builtin_nontemporal_store(m, out + base + ks);
    }
}

// ---------------------------------------------------------------------------
// FUSED v2. One wave per token row; 8 waves/block.
// Phase order engineered around the barrier's implicit vmcnt(0) drain:
//   0: cooperative W1 -> LDS (2 dwordx4/thread) + query load.  [small vmem]
//   1: __syncthreads (drains only the tiny stage, NOT the u row).
//   2: issue u-row vec4 loads (vmcnt domain)  -- then immediately
//      MLP: 64 x { ds_read_b32 W1s (lgkm domain) + readlane(qv) + fmaf }.
//      The ~800-cycle MLP hides the u HBM latency; the two wait counters
//      are independent so no vmcnt wait occurs until the mask phase.
//   3: Sigma epilogue (verified math) -> j0/j1/j2; Sigma store.
//   4: mask row with REGISTER geometry (no LDS table at all).
// LDS: 16 KB W1 only. No G4 table, no ds_bpermute in the MLP.
// ---------------------------------------------------------------------------
__global__ __launch_bounds__(512, 6)
void fused_v2(const float* __restrict__ query,  // (NTOK, 64)
              const float* __restrict__ W1,     // (64, 64)
              const float* __restrict__ b1,     // (64)
              const float* __restrict__ W2,     // (64, 3)
              const float* __restrict__ b2,     // (3)
              const float* __restrict__ u,      // (NTOK*577) flat
              const float* __restrict__ temp,   // (1)
              float* __restrict__ out)          // mask then Sigma
{
    __shared__ float W1s[DD * DD];               // 16 KB

    f4* __restrict__ SigOut = (f4*)(out + MASK_ELEMS);
    const int q     = blockIdx.x;                // 0..576
    const int chunk = blockIdx.y;                // 0..11
    const int tid   = threadIdx.x;
    const int wave  = tid >> 6, lane = tid & 63;

    const int token = (chunk * WAVES_PER_BLOCK + wave) * QT + q;
    const unsigned base = (unsigned)token * (unsigned)QT;
    const int h  = (int)((0u - base) & 3u);      // scalars to 16B align
    const int NV = (QT - h) >> 2;                // 143 or 144 vec4s
    const float* __restrict__ up = u   + base + h;
    float*       __restrict__ mp = out + base + h;

    // ---- phase 0: stage W1 -> LDS; load this wave's query element ----
    ((f4*)W1s)[tid]       = ((const f4*)W1)[tid];
    ((f4*)W1s)[tid + 512] = ((const f4*)W1)[tid + 512];
    const float qv   = query[(size_t)token * DD + lane];
    const float tval = temp[0];
    __syncthreads();                             // drains only the small stage

    // ---- phase 2a: issue u-row loads NOW (drain under the MLP) ----
    const f4 uu0 = *(const f4*)(up + 4 * lane);
    const f4 uu1 = *(const f4*)(up + 4 * (64 + lane));
    const int idx2 = 128 + lane;
    f4 uu2 = {};
    if (idx2 < NV) uu2 = *(const f4*)(up + 4 * idx2);
    const int scnt = QT - 4 * NV;                // 1 or 5 leftovers
    int ks = 0; float us = 0.0f;
    if (lane < scnt) {
        ks = (lane < h) ? lane : (h + 4 * NV + (lane - h));
        us = u[base + ks];
    }

    // ---- phase 2b: MLP (exact verified chain; W1 via LDS, readlane bcast) --
    float acc = b1[lane];
#pragma unroll
    for (int i = 0; i < DD; ++i) {
        const float x = __int_as_float(
            __builtin_amdgcn_readlane(__float_as_int(qv), i));
        acc = fmaf(x, W1s[i * DD + lane], acc);  // ds_read_b32, 2-way free
    }
    const float hg = 0.5f * acc * (1.0f + erff(acc * 0.7071067811865476f));

    float p0 = hg * W2[lane * 3 + 0];
    float p1 = hg * W2[lane * 3 + 1];
    float p2 = hg * W2[lane * 3 + 2];
#pragma unroll
    for (int off = 32; off > 0; off >>= 1) {     // butterfly: all lanes get sums
        p0 += __shfl_xor(p0, off);
        p1 += __shfl_xor(p1, off);
        p2 += __shfl_xor(p2, off);
    }
    const float sy  = expf(p0 + b2[0]) + 1.0f;   // precise ocml for Sigma
    const float sx  = expf(p1 + b2[1]) + 1.0f;
    const float rho = tanhf(p2 + b2[2]) * 0.99f;
    const float cov = sy * sx * rho;
    const float Sx = sy * sy, Sw = sx * sx, Sy = cov;
    if (lane == 0) {
        f4 s; s.x = Sx; s.y = Sy; s.z = Sy; s.w = Sw;
        SigOut[token] = s;                       // Sigma output region
    }

    const float rdet = __fdividef(1.0f, fmaf(Sx, Sw, -Sy * Sy));
    const float j0 =  0.5f * Sw * rdet;          // 0.5*inv00
    const float j1 = -Sy * rdet;                 // inv01 (x2, x0.5 cancel)
    const float j2 =  0.5f * Sx * rdet;          // 0.5*inv11

    // per-q scalars (block-uniform -> SALU)
    const int qm1 = (q > 0) ? q - 1 : 0;
    const int qr  = (int)((unsigned)qm1 / 24u);
    const int qc  = qm1 - qr * 24;
    const float fqr = (float)qr, fqc = (float)qc;
    const float sc  = (q == 0) ? 0.0f : 1.0f;    // zero the q==0 (CLS) row

    // scalar-uniform temperature branch: hot path has NO predicated cold ops
    const float invT = __int_as_float(__builtin_amdgcn_readfirstlane(
                           __float_as_int(__fdividef(1.0f, tval))));
    if (invT == 1.0f)
        mask_row<true >(h, NV, lane, uu0, uu1, uu2, idx2, scnt, ks, us,
                        fqr, fqc, sc, j0, j1, j2, invT, mp, out, base);
    else
        mask_row<false>(h, NV, lane, uu0, uu1, uu2, idx2, scnt, ks, us,
                        fqr, fqc, sc, j0, j1, j2, invT, mp, out, base);
}

extern "C" void kernel_launch(void* const* d_in, const int* in_sizes, int n_in,
                              void* d_out, int out_size, void* d_ws, size_t ws_size,
                              hipStream_t stream) {
    const float* query = (const float*)d_in[0];
    const float* W1    = (const float*)d_in[1];
    const float* b1    = (const float*)d_in[2];
    const float* W2    = (const float*)d_in[3];
    const float* b2    = (const float*)d_in[4];
    // d_in[5] = dists: closed form inside fused_v2
    const float* u     = (const float*)d_in[6];
    const float* temp  = (const float*)d_in[7];
    float* out = (float*)d_out;

    fused_v2<<<dim3(QT, CHUNKS), dim3(512), 0, stream>>>(
        query, W1, b1, W2, b2, u, temp, out);
}